// Round 1
// baseline (417.921 us; speedup 1.0000x reference)
//
#include <hip/hip_runtime.h>
#include <math.h>

// Workspace layout (floats):
//   [0,256)    Tu  : upper-triangular Re(U^H M U), off-diagonal pre-doubled
//   [256,800)  S   : accumulators S[b][q], 32*17
//   [800,832)  n   : squared norms per batch
#define WS_TU 0
#define WS_S  256
#define WS_N  800

// float4-granularity XOR swizzle for LDS bank spreading
#define SWZ(F) ((F) ^ (((F) >> 3) & 7))

__device__ inline float2 cmul2(float2 a, float2 b) {
  return make_float2(a.x * b.x - a.y * b.y, a.x * b.y + a.y * b.x);
}

// ring-of-CNOT permutation: qubit k <-> bit (3-k). Apply CNOT(0,1),(1,2),(2,3),(3,0) in order.
__device__ inline int ringperm(int x) {
  if ((x >> 3) & 1) x ^= 4;
  if ((x >> 2) & 1) x ^= 2;
  if ((x >> 1) & 1) x ^= 1;
  if (x & 1)        x ^= 8;
  return x;
}

// element (r,c) of kron_{k=0..3} [ Ry(p[3k+2]) Rz(p[3k+1]) Ry(p[3k]) ]
__device__ inline float2 yzy_elem(const float* wgt, int layer, int r, int c) {
  float2 prod = make_float2(1.f, 0.f);
#pragma unroll
  for (int k = 0; k < 4; k++) {
    float t0 = wgt[layer * 12 + 3 * k + 0];
    float t1 = wgt[layer * 12 + 3 * k + 1];
    float t2 = wgt[layer * 12 + 3 * k + 2];
    float s0, c0, s1, c1, s2, c2;
    sincosf(0.5f * t0, &s0, &c0);
    sincosf(0.5f * t1, &s1, &c1);
    sincosf(0.5f * t2, &s2, &c2);
    float A = c2 * c0, B = s2 * s0, C = c2 * s0, D = s2 * c0;
    // m = Ry(t2) Rz(t1) Ry(t0), e = exp(-i t1/2)
    float2 m00 = make_float2( c1 * (A - B), -s1 * (A + B));
    float2 m01 = make_float2(-c1 * (C + D),  s1 * (C - D));
    float2 m10 = make_float2( c1 * (C + D),  s1 * (C - D));
    float2 m11 = make_float2( c1 * (A - B),  s1 * (A + B));
    int rb = (r >> (3 - k)) & 1, cb = (c >> (3 - k)) & 1;
    float2 mm = rb ? (cb ? m11 : m10) : (cb ? m01 : m00);
    prod = cmul2(prod, mm);
  }
  return prod;
}

__global__ void build_T_kernel(const float* __restrict__ wgt, float* __restrict__ ws) {
  __shared__ float2 U[256], Y[256], W[256];
  const int t = threadIdx.x;
  const int r = t >> 4, c = t & 15;

  // U = YZY layer 0
  U[t] = yzy_elem(wgt, 0, r, c);
  __syncthreads();
  // U = ring @ U  (row scatter)
  W[ringperm(r) * 16 + c] = U[t];
  __syncthreads(); U[t] = W[t]; __syncthreads();
  // U = YZY1 @ U
  Y[t] = yzy_elem(wgt, 1, r, c);
  __syncthreads();
  {
    float2 s = make_float2(0.f, 0.f);
#pragma unroll
    for (int k = 0; k < 16; k++) {
      float2 pr = cmul2(Y[r * 16 + k], U[k * 16 + c]);
      s.x += pr.x; s.y += pr.y;
    }
    W[t] = s;
  }
  __syncthreads(); U[t] = W[t]; __syncthreads();
  // U = ring @ U
  W[ringperm(r) * 16 + c] = U[t];
  __syncthreads(); U[t] = W[t]; __syncthreads();
  // U = YZY2 @ U
  Y[t] = yzy_elem(wgt, 2, r, c);
  __syncthreads();
  {
    float2 s = make_float2(0.f, 0.f);
#pragma unroll
    for (int k = 0; k < 16; k++) {
      float2 pr = cmul2(Y[r * 16 + k], U[k * 16 + c]);
      s.x += pr.x; s.y += pr.y;
    }
    W[t] = s;
  }
  __syncthreads(); U[t] = W[t]; __syncthreads();
  // Y = M @ U  with M = X^{\otimes 4}: row y <- row (y^15)
  Y[t] = U[(r ^ 15) * 16 + c];
  __syncthreads();
  // temp[r][c] = sum_k conj(U[k][r]) * Y[k][c]; take real part
  float s_re = 0.f;
#pragma unroll
  for (int k = 0; k < 16; k++) {
    float2 u = U[k * 16 + r], m = Y[k * 16 + c];
    s_re += u.x * m.x + u.y * m.y;
  }
  float tu;
  if (r == c)      tu = s_re;
  else if (c > r)  tu = 2.f * s_re;
  else             tu = 0.f;
  ws[WS_TU + t] = tu;
}

// ---- quadratic-form cores (Tu upper-triangular, off-diag pre-doubled) ----

__device__ inline float tri16(const float* v, const float* Tu) {
  float s = 0.f;
#pragma unroll
  for (int i = 0; i < 16; i++) {
    float wv = Tu[i * 16 + i] * v[i];
#pragma unroll
    for (int j = i + 1; j < 16; j++) wv = fmaf(Tu[i * 16 + j], v[j], wv);
    s = fmaf(v[i], wv, s);
  }
  return s;
}

__device__ inline float tri16x4(const float4* v, const float* Tu) {
  float4 acc = make_float4(0.f, 0.f, 0.f, 0.f);
#pragma unroll
  for (int i = 0; i < 16; i++) {
    float tii = Tu[i * 16 + i];
    float4 wv = make_float4(tii * v[i].x, tii * v[i].y, tii * v[i].z, tii * v[i].w);
#pragma unroll
    for (int j = i + 1; j < 16; j++) {
      float tij = Tu[i * 16 + j];
      wv.x = fmaf(tij, v[j].x, wv.x);
      wv.y = fmaf(tij, v[j].y, wv.y);
      wv.z = fmaf(tij, v[j].z, wv.z);
      wv.w = fmaf(tij, v[j].w, wv.w);
    }
    acc.x = fmaf(v[i].x, wv.x, acc.x);
    acc.y = fmaf(v[i].y, wv.y, acc.y);
    acc.z = fmaf(v[i].z, wv.z, acc.z);
    acc.w = fmaf(v[i].w, wv.w, acc.w);
  }
  return acc.x + acc.y + acc.z + acc.w;
}

__device__ inline void wave_atomic_add(float val, float* dst) {
#pragma unroll
  for (int off = 32; off > 0; off >>= 1) val += __shfl_down(val, off, 64);
  if ((threadIdx.x & 63) == 0) atomicAdd(dst, val);
}

// window at bit position P (2 <= P <= 10) inside a 2^14-float contiguous chunk.
// Each thread owns 4 consecutive c-values of one (a)-block: one float4 per i.
template <int P>
__device__ inline float windowP(const float4* lds, const float* Tu) {
  const int t = threadIdx.x;
  const int a = t >> (P - 2);
  const int cb = t & ((1 << (P - 2)) - 1);
  const int base = (a << (P + 2)) + cb;  // float4 index
  float4 v[16];
#pragma unroll
  for (int i = 0; i < 16; i++) v[i] = lds[SWZ(base + (i << (P - 2)))];
  return tri16x4(v, Tu);
}

__global__ __launch_bounds__(256) void passA_kernel(const float* __restrict__ vb,
                                                    float* ws) {
  __shared__ float4 lds[4096];  // 64 KB
  const int t = threadIdx.x;
  const int b = blockIdx.x >> 6;
  const int chunk = blockIdx.x & 63;
  const float4* src = ((const float4*)vb) + ((size_t)b << 18) + ((size_t)chunk << 12);

  float nsum = 0.f;
#pragma unroll
  for (int j = 0; j < 16; j++) {
    float4 v = src[(j << 8) + t];
    nsum = fmaf(v.x, v.x, nsum);
    nsum = fmaf(v.y, v.y, nsum);
    nsum = fmaf(v.z, v.z, nsum);
    nsum = fmaf(v.w, v.w, nsum);
    lds[SWZ((j << 8) + t)] = v;
  }
  wave_atomic_add(nsum, ws + WS_N + b);
  __syncthreads();

  const float* Tu = ws + WS_TU;
  float* S = ws + WS_S + b * 17;

  // p = 0 (q = 16): groups are 16 contiguous floats
  {
    float acc = 0.f;
    for (int g = t; g < 1024; g += 256) {
      float4 q0 = lds[SWZ(4 * g + 0)];
      float4 q1 = lds[SWZ(4 * g + 1)];
      float4 q2 = lds[SWZ(4 * g + 2)];
      float4 q3 = lds[SWZ(4 * g + 3)];
      float v[16] = {q0.x, q0.y, q0.z, q0.w, q1.x, q1.y, q1.z, q1.w,
                     q2.x, q2.y, q2.z, q2.w, q3.x, q3.y, q3.z, q3.w};
      acc += tri16(v, Tu);
    }
    wave_atomic_add(acc, S + 16);
  }
  // p = 1 (q = 15): two interleaved groups per 32-float block
  {
    float acc = 0.f;
    for (int ab = t; ab < 512; ab += 256) {
      float4 q[8];
#pragma unroll
      for (int k = 0; k < 8; k++) q[k] = lds[SWZ(8 * ab + k)];
      float v0[16], v1[16];
#pragma unroll
      for (int k = 0; k < 8; k++) {
        v0[2 * k]     = q[k].x;
        v1[2 * k]     = q[k].y;
        v0[2 * k + 1] = q[k].z;
        v1[2 * k + 1] = q[k].w;
      }
      acc += tri16(v0, Tu) + tri16(v1, Tu);
    }
    wave_atomic_add(acc, S + 15);
  }
  // p = 2..10  ->  q = 14..6
  wave_atomic_add(windowP<2>(lds, Tu),  S + 14);
  wave_atomic_add(windowP<3>(lds, Tu),  S + 13);
  wave_atomic_add(windowP<4>(lds, Tu),  S + 12);
  wave_atomic_add(windowP<5>(lds, Tu),  S + 11);
  wave_atomic_add(windowP<6>(lds, Tu),  S + 10);
  wave_atomic_add(windowP<7>(lds, Tu),  S + 9);
  wave_atomic_add(windowP<8>(lds, Tu),  S + 8);
  wave_atomic_add(windowP<9>(lds, Tu),  S + 7);
  wave_atomic_add(windowP<10>(lds, Tu), S + 6);
}

// pass B: windows p = 11..16 (q = 5..0). Tile = 512 rows (bits 11..19) x 32 floats (low bits).
template <int PB>
__device__ inline float windowB(const float4* lds, const float* Tu) {
  const int t = threadIdx.x;
  const int c4 = t & 7;
  const int g = t >> 3;  // 5 free hi-bits
  const int glo = g & ((1 << PB) - 1);
  const int ghi = g >> PB;
  float4 v[16];
#pragma unroll
  for (int i = 0; i < 16; i++) {
    int row = (ghi << (PB + 4)) | (i << PB) | glo;
    v[i] = lds[row * 8 + c4];
  }
  return tri16x4(v, Tu);
}

__global__ __launch_bounds__(256) void passB_kernel(const float* __restrict__ vb,
                                                    float* ws) {
  __shared__ float4 lds[4096];  // [row 0..512) x [c4 0..8)
  const int t = threadIdx.x;
  const int b = blockIdx.x >> 6;
  const int tile = blockIdx.x & 63;
  const float4* src = ((const float4*)vb) + ((size_t)b << 18) + tile * 8;

#pragma unroll
  for (int j = 0; j < 16; j++) {
    int x = (j << 8) + t;
    int row = x >> 3, c4 = x & 7;
    lds[x] = src[row * 512 + c4];
  }
  __syncthreads();

  const float* Tu = ws + WS_TU;
  float* S = ws + WS_S + b * 17;

  wave_atomic_add(windowB<0>(lds, Tu), S + 5);
  wave_atomic_add(windowB<1>(lds, Tu), S + 4);
  wave_atomic_add(windowB<2>(lds, Tu), S + 3);
  wave_atomic_add(windowB<3>(lds, Tu), S + 2);
  wave_atomic_add(windowB<4>(lds, Tu), S + 1);
  wave_atomic_add(windowB<5>(lds, Tu), S + 0);
}

__global__ void finalize_kernel(const float* __restrict__ ws, float* __restrict__ out) {
  int i = blockIdx.x * 256 + threadIdx.x;
  if (i < 544) {
    int b = i / 17;
    float n = ws[WS_N + b];
    n = fmaxf(n, 1e-24f);
    out[i] = ws[WS_S + i] / n;
  }
}

extern "C" void kernel_launch(void* const* d_in, const int* in_sizes, int n_in,
                              void* d_out, int out_size, void* d_ws, size_t ws_size,
                              hipStream_t stream) {
  const float* vb  = (const float*)d_in[0];
  const float* wgt = (const float*)d_in[1];
  float* out = (float*)d_out;
  float* ws  = (float*)d_ws;

  // zero Tu + S + n accumulators (re-done every launch; replay-safe)
  hipMemsetAsync(d_ws, 0, 4096, stream);
  build_T_kernel<<<1, 256, 0, stream>>>(wgt, ws);
  passA_kernel<<<2048, 256, 0, stream>>>(vb, ws);
  passB_kernel<<<2048, 256, 0, stream>>>(vb, ws);
  finalize_kernel<<<3, 256, 0, stream>>>(ws, out);
}

// Round 2
// 197.209 us; speedup vs baseline: 2.1192x; 2.1192x over previous
//
#include <hip/hip_runtime.h>
#include <math.h>

// Workspace layout (floats):
//   [0,256)    T   : full symmetric Re(U^H M U)
//   [256,800)  S   : accumulators S[b][q], 32*17
//   [800,832)  n   : squared norms per batch
#define WS_TU 0
#define WS_S  256
#define WS_N  800

typedef _Float16 half8 __attribute__((ext_vector_type(8)));
typedef float f32x4 __attribute__((ext_vector_type(4)));

__device__ inline float2 cmul2(float2 a, float2 b) {
  return make_float2(a.x * b.x - a.y * b.y, a.x * b.y + a.y * b.x);
}

__device__ inline int ringperm(int x) {
  if ((x >> 3) & 1) x ^= 4;
  if ((x >> 2) & 1) x ^= 2;
  if ((x >> 1) & 1) x ^= 1;
  if (x & 1)        x ^= 8;
  return x;
}

__device__ inline float2 yzy_elem(const float* wgt, int layer, int r, int c) {
  float2 prod = make_float2(1.f, 0.f);
#pragma unroll
  for (int k = 0; k < 4; k++) {
    float t0 = wgt[layer * 12 + 3 * k + 0];
    float t1 = wgt[layer * 12 + 3 * k + 1];
    float t2 = wgt[layer * 12 + 3 * k + 2];
    float s0, c0, s1, c1, s2, c2;
    sincosf(0.5f * t0, &s0, &c0);
    sincosf(0.5f * t1, &s1, &c1);
    sincosf(0.5f * t2, &s2, &c2);
    float A = c2 * c0, B = s2 * s0, C = c2 * s0, D = s2 * c0;
    float2 m00 = make_float2( c1 * (A - B), -s1 * (A + B));
    float2 m01 = make_float2(-c1 * (C + D),  s1 * (C - D));
    float2 m10 = make_float2( c1 * (C + D),  s1 * (C - D));
    float2 m11 = make_float2( c1 * (A - B),  s1 * (A + B));
    int rb = (r >> (3 - k)) & 1, cb = (c >> (3 - k)) & 1;
    float2 mm = rb ? (cb ? m11 : m10) : (cb ? m01 : m00);
    prod = cmul2(prod, mm);
  }
  return prod;
}

__global__ void build_T_kernel(const float* __restrict__ wgt, float* __restrict__ ws) {
  __shared__ float2 U[256], Y[256], W[256];
  const int t = threadIdx.x;
  const int r = t >> 4, c = t & 15;

  U[t] = yzy_elem(wgt, 0, r, c);
  __syncthreads();
  W[ringperm(r) * 16 + c] = U[t];
  __syncthreads(); U[t] = W[t]; __syncthreads();
  Y[t] = yzy_elem(wgt, 1, r, c);
  __syncthreads();
  {
    float2 s = make_float2(0.f, 0.f);
#pragma unroll
    for (int k = 0; k < 16; k++) {
      float2 pr = cmul2(Y[r * 16 + k], U[k * 16 + c]);
      s.x += pr.x; s.y += pr.y;
    }
    W[t] = s;
  }
  __syncthreads(); U[t] = W[t]; __syncthreads();
  W[ringperm(r) * 16 + c] = U[t];
  __syncthreads(); U[t] = W[t]; __syncthreads();
  Y[t] = yzy_elem(wgt, 2, r, c);
  __syncthreads();
  {
    float2 s = make_float2(0.f, 0.f);
#pragma unroll
    for (int k = 0; k < 16; k++) {
      float2 pr = cmul2(Y[r * 16 + k], U[k * 16 + c]);
      s.x += pr.x; s.y += pr.y;
    }
    W[t] = s;
  }
  __syncthreads(); U[t] = W[t]; __syncthreads();
  Y[t] = U[(r ^ 15) * 16 + c];
  __syncthreads();
  float s_re = 0.f;
#pragma unroll
  for (int k = 0; k < 16; k++) {
    float2 u = U[k * 16 + r], m = Y[k * 16 + c];
    s_re += u.x * m.x + u.y * m.y;
  }
  ws[WS_TU + t] = s_re;  // full symmetric T
}

// XOR-fold swizzle on 16B-block index: spreads any window stride over >=8 bank slots
__device__ inline int swzB(int B) {
  int h = B >> 3;
  int f = (h ^ (h >> 3) ^ (h >> 6)) & 7;
  return B ^ f;
}

__device__ inline void wave_atomic_add(float val, float* dst) {
#pragma unroll
  for (int off = 32; off > 0; off >>= 1) val += __shfl_down(val, off, 64);
  if ((threadIdx.x & 63) == 0) atomicAdd(dst, val);
}

// Gram-window via MFMA. LDS layout: 2048 16B blocks of 8 f16, block index swizzled.
// Window field at LDS-pos bits [P,P+4), P in [3,10]. k-slot = (v=pos[0:3), rest).
template <int P>
__device__ inline float windowM(const half8* __restrict__ HB, const float* __restrict__ TS) {
  const int t = threadIdx.x;
  const int w = t >> 6, l = t & 63, g = l >> 4, i = l & 15;
  f32x4 hh = {0.f, 0.f, 0.f, 0.f};
#pragma unroll
  for (int s = 0; s < 8; s++) {
    int rest = (w << 5) | (s << 2) | g;  // 7 bits
    int rlow = rest & ((1 << (P - 3)) - 1);
    int rhigh = rest >> (P - 3);
    int pos = (rlow << 3) | (i << P) | (rhigh << (P + 4));
    half8 fr = HB[swzB(pos >> 3)];
    hh = __builtin_amdgcn_mfma_f32_16x16x32_f16(fr, fr, hh, 0, 0, 0);
  }
  float part = 0.f;
#pragma unroll
  for (int reg = 0; reg < 4; reg++) {
    part = fmaf(TS[((g * 4 + reg) << 4) + i], hh[reg], part);
  }
  return part;
}

// modes: 0 = identity contiguous chunk (p=3..10) + norms
//        1 = rot+3 contiguous chunk    (p=0,1,2 -> P=3,4,5)
//        2 = strided row tile          (p=11..16 -> P=5..10)
__global__ __launch_bounds__(256) void passAll_kernel(const float* __restrict__ vb,
                                                      float* ws) {
  __shared__ half8 HB[2048];   // 32 KB
  __shared__ float TS[256];
  const int t = threadIdx.x;
  const int bid = blockIdx.x;
  const int mode = bid >> 11;
  const int wid = bid & 2047;
  const int b = wid >> 6;
  const int chunk = wid & 63;

  TS[t] = ws[WS_TU + t];

  if (mode == 0) {
    const float4* src4 = ((const float4*)vb) + ((size_t)b << 18) + ((size_t)chunk << 12);
    float nsum = 0.f;
#pragma unroll
    for (int j = 0; j < 8; j++) {
      int B = j * 256 + t;
      float4 a = src4[2 * B], c = src4[2 * B + 1];
      nsum = fmaf(a.x, a.x, nsum); nsum = fmaf(a.y, a.y, nsum);
      nsum = fmaf(a.z, a.z, nsum); nsum = fmaf(a.w, a.w, nsum);
      nsum = fmaf(c.x, c.x, nsum); nsum = fmaf(c.y, c.y, nsum);
      nsum = fmaf(c.z, c.z, nsum); nsum = fmaf(c.w, c.w, nsum);
      half8 h;
      h[0] = (_Float16)a.x; h[1] = (_Float16)a.y; h[2] = (_Float16)a.z; h[3] = (_Float16)a.w;
      h[4] = (_Float16)c.x; h[5] = (_Float16)c.y; h[6] = (_Float16)c.z; h[7] = (_Float16)c.w;
      HB[swzB(B)] = h;
    }
    wave_atomic_add(nsum, ws + WS_N + b);
  } else if (mode == 1) {
    // LDS pos = (g & 2047)*8 + (g >> 11): global bit j -> LDS bit (j+3) mod 14
    const float* srcf = vb + ((size_t)b << 20) + ((size_t)chunk << 14);
#pragma unroll
    for (int j = 0; j < 8; j++) {
      int B = j * 256 + t;
      half8 h;
#pragma unroll
      for (int e = 0; e < 8; e++) h[e] = (_Float16)srcf[e * 2048 + B];
      HB[swzB(B)] = h;
    }
  } else {
    // tile: 32 consecutive floats x 512 rows at stride 2048 floats
    const float4* src4 = ((const float4*)vb) + ((size_t)b << 18) + chunk * 8;
#pragma unroll
    for (int j = 0; j < 8; j++) {
      int B = j * 256 + t;
      int row = B >> 2;
      int c4 = (B & 3) * 2;
      float4 a = src4[row * 512 + c4], c = src4[row * 512 + c4 + 1];
      half8 h;
      h[0] = (_Float16)a.x; h[1] = (_Float16)a.y; h[2] = (_Float16)a.z; h[3] = (_Float16)a.w;
      h[4] = (_Float16)c.x; h[5] = (_Float16)c.y; h[6] = (_Float16)c.z; h[7] = (_Float16)c.w;
      HB[swzB(B)] = h;
    }
  }
  __syncthreads();

  float* S = ws + WS_S + b * 17;

  if (mode == 0) {
    // window p = P, target S + (16 - p)
    wave_atomic_add(windowM<3>(HB, TS),  S + 13);
    wave_atomic_add(windowM<4>(HB, TS),  S + 12);
    wave_atomic_add(windowM<5>(HB, TS),  S + 11);
    wave_atomic_add(windowM<6>(HB, TS),  S + 10);
    wave_atomic_add(windowM<7>(HB, TS),  S + 9);
    wave_atomic_add(windowM<8>(HB, TS),  S + 8);
    wave_atomic_add(windowM<9>(HB, TS),  S + 7);
    wave_atomic_add(windowM<10>(HB, TS), S + 6);
  } else if (mode == 1) {
    // p = P - 3 in {0,1,2}, target S + (16 - p)
    wave_atomic_add(windowM<3>(HB, TS), S + 16);
    wave_atomic_add(windowM<4>(HB, TS), S + 15);
    wave_atomic_add(windowM<5>(HB, TS), S + 14);
  } else {
    // p = P + 6 in {11..16}, target S + (10 - P)
    wave_atomic_add(windowM<5>(HB, TS),  S + 5);
    wave_atomic_add(windowM<6>(HB, TS),  S + 4);
    wave_atomic_add(windowM<7>(HB, TS),  S + 3);
    wave_atomic_add(windowM<8>(HB, TS),  S + 2);
    wave_atomic_add(windowM<9>(HB, TS),  S + 1);
    wave_atomic_add(windowM<10>(HB, TS), S + 0);
  }
}

__global__ void finalize_kernel(const float* __restrict__ ws, float* __restrict__ out) {
  int i = blockIdx.x * 256 + threadIdx.x;
  if (i < 544) {
    int b = i / 17;
    float n = ws[WS_N + b];
    n = fmaxf(n, 1e-24f);
    out[i] = ws[WS_S + i] / n;
  }
}

extern "C" void kernel_launch(void* const* d_in, const int* in_sizes, int n_in,
                              void* d_out, int out_size, void* d_ws, size_t ws_size,
                              hipStream_t stream) {
  const float* vb  = (const float*)d_in[0];
  const float* wgt = (const float*)d_in[1];
  float* out = (float*)d_out;
  float* ws  = (float*)d_ws;

  hipMemsetAsync(d_ws, 0, 4096, stream);
  build_T_kernel<<<1, 256, 0, stream>>>(wgt, ws);
  passAll_kernel<<<6144, 256, 0, stream>>>(vb, ws);
  finalize_kernel<<<3, 256, 0, stream>>>(ws, out);
}

// Round 3
// 81.676 us; speedup vs baseline: 5.1168x; 2.4145x over previous
//
#include <hip/hip_runtime.h>
#include <math.h>

// Workspace layout (floats):
//   [0,256)          T     : full symmetric Re(U^H M U)
//   [256,800)        S     : atomic-fallback accumulators S[b][q]
//   [800,832)        n     : atomic-fallback squared norms
//   [1024,35840)     Spart : partials [b][q][chunk]  32*17*64
//   [35840,37888)    npart : norm partials [b][chunk] 32*64
#define WS_TU    0
#define WS_S     256
#define WS_N     800
#define WS_PART  1024
#define WS_NPART 35840
#define WS_NEED_BYTES ((WS_NPART + 2048) * 4)

typedef _Float16 half8 __attribute__((ext_vector_type(8)));
typedef float f32x4 __attribute__((ext_vector_type(4)));

__device__ inline float2 cmul2(float2 a, float2 b) {
  return make_float2(a.x * b.x - a.y * b.y, a.x * b.y + a.y * b.x);
}

__device__ inline int ringperm(int x) {
  if ((x >> 3) & 1) x ^= 4;
  if ((x >> 2) & 1) x ^= 2;
  if ((x >> 1) & 1) x ^= 1;
  if (x & 1)        x ^= 8;
  return x;
}

__device__ inline float2 yzy_elem(const float* wgt, int layer, int r, int c) {
  float2 prod = make_float2(1.f, 0.f);
#pragma unroll
  for (int k = 0; k < 4; k++) {
    float t0 = wgt[layer * 12 + 3 * k + 0];
    float t1 = wgt[layer * 12 + 3 * k + 1];
    float t2 = wgt[layer * 12 + 3 * k + 2];
    float s0, c0, s1, c1, s2, c2;
    sincosf(0.5f * t0, &s0, &c0);
    sincosf(0.5f * t1, &s1, &c1);
    sincosf(0.5f * t2, &s2, &c2);
    float A = c2 * c0, B = s2 * s0, C = c2 * s0, D = s2 * c0;
    float2 m00 = make_float2( c1 * (A - B), -s1 * (A + B));
    float2 m01 = make_float2(-c1 * (C + D),  s1 * (C - D));
    float2 m10 = make_float2( c1 * (C + D),  s1 * (C - D));
    float2 m11 = make_float2( c1 * (A - B),  s1 * (A + B));
    int rb = (r >> (3 - k)) & 1, cb = (c >> (3 - k)) & 1;
    float2 mm = rb ? (cb ? m11 : m10) : (cb ? m01 : m00);
    prod = cmul2(prod, mm);
  }
  return prod;
}

__global__ void build_T_kernel(const float* __restrict__ wgt, float* __restrict__ ws) {
  __shared__ float2 U[256], Y[256], W[256];
  const int t = threadIdx.x;
  const int r = t >> 4, c = t & 15;

  U[t] = yzy_elem(wgt, 0, r, c);
  __syncthreads();
  W[ringperm(r) * 16 + c] = U[t];
  __syncthreads(); U[t] = W[t]; __syncthreads();
  Y[t] = yzy_elem(wgt, 1, r, c);
  __syncthreads();
  {
    float2 s = make_float2(0.f, 0.f);
#pragma unroll
    for (int k = 0; k < 16; k++) {
      float2 pr = cmul2(Y[r * 16 + k], U[k * 16 + c]);
      s.x += pr.x; s.y += pr.y;
    }
    W[t] = s;
  }
  __syncthreads(); U[t] = W[t]; __syncthreads();
  W[ringperm(r) * 16 + c] = U[t];
  __syncthreads(); U[t] = W[t]; __syncthreads();
  Y[t] = yzy_elem(wgt, 2, r, c);
  __syncthreads();
  {
    float2 s = make_float2(0.f, 0.f);
#pragma unroll
    for (int k = 0; k < 16; k++) {
      float2 pr = cmul2(Y[r * 16 + k], U[k * 16 + c]);
      s.x += pr.x; s.y += pr.y;
    }
    W[t] = s;
  }
  __syncthreads(); U[t] = W[t]; __syncthreads();
  Y[t] = U[(r ^ 15) * 16 + c];
  __syncthreads();
  float s_re = 0.f;
#pragma unroll
  for (int k = 0; k < 16; k++) {
    float2 u = U[k * 16 + r], m = Y[k * 16 + c];
    s_re += u.x * m.x + u.y * m.y;
  }
  ws[WS_TU + t] = s_re;  // full symmetric T
}

// XOR-fold swizzle on 16B-block index
__device__ inline int swzB(int B) {
  int h = B >> 3;
  int f = (h ^ (h >> 3) ^ (h >> 6)) & 7;
  return B ^ f;
}

__device__ inline float wave_reduce(float val) {
#pragma unroll
  for (int off = 32; off > 0; off >>= 1) val += __shfl_down(val, off, 64);
  return val;
}

// Gram-window via MFMA. LDS: 2048 16B blocks of 8 f16, block index swizzled.
template <int P>
__device__ inline float windowM(const half8* __restrict__ HB, const float* __restrict__ TS) {
  const int t = threadIdx.x;
  const int w = t >> 6, l = t & 63, g = l >> 4, i = l & 15;
  f32x4 hh = {0.f, 0.f, 0.f, 0.f};
#pragma unroll
  for (int s = 0; s < 8; s++) {
    int rest = (w << 5) | (s << 2) | g;  // 7 bits
    int rlow = rest & ((1 << (P - 3)) - 1);
    int rhigh = rest >> (P - 3);
    int pos = (rlow << 3) | (i << P) | (rhigh << (P + 4));
    half8 fr = HB[swzB(pos >> 3)];
    hh = __builtin_amdgcn_mfma_f32_16x16x32_f16(fr, fr, hh, 0, 0, 0);
  }
  float part = 0.f;
#pragma unroll
  for (int reg = 0; reg < 4; reg++) {
    part = fmaf(TS[((g * 4 + reg) << 4) + i], hh[reg], part);
  }
  return part;
}

// modes: 0 = identity contiguous chunk (p=3..10) + norms
//        1 = rot+3 contiguous chunk    (p=0,1,2 -> P=3,4,5)
//        2 = strided row tile          (p=11..16 -> P=5..10)
__global__ __launch_bounds__(256) void passAll_kernel(const float* __restrict__ vb,
                                                      float* ws, int use_part) {
  __shared__ half8 HB[2048];   // 32 KB
  __shared__ float TS[256];
  __shared__ float red[40];    // [win 0..8)x4 waves + norm at 32..36
  const int t = threadIdx.x;
  const int w = t >> 6;
  const int lane = t & 63;
  const int bid = blockIdx.x;
  const int mode = bid >> 11;
  const int wid = bid & 2047;
  const int b = wid >> 6;
  const int chunk = wid & 63;

  TS[t] = ws[WS_TU + t];

  if (mode == 0) {
    const float4* src4 = ((const float4*)vb) + ((size_t)b << 18) + ((size_t)chunk << 12);
    float nsum = 0.f;
#pragma unroll
    for (int j = 0; j < 8; j++) {
      int B = j * 256 + t;
      float4 a = src4[2 * B], c = src4[2 * B + 1];
      nsum = fmaf(a.x, a.x, nsum); nsum = fmaf(a.y, a.y, nsum);
      nsum = fmaf(a.z, a.z, nsum); nsum = fmaf(a.w, a.w, nsum);
      nsum = fmaf(c.x, c.x, nsum); nsum = fmaf(c.y, c.y, nsum);
      nsum = fmaf(c.z, c.z, nsum); nsum = fmaf(c.w, c.w, nsum);
      half8 h;
      h[0] = (_Float16)a.x; h[1] = (_Float16)a.y; h[2] = (_Float16)a.z; h[3] = (_Float16)a.w;
      h[4] = (_Float16)c.x; h[5] = (_Float16)c.y; h[6] = (_Float16)c.z; h[7] = (_Float16)c.w;
      HB[swzB(B)] = h;
    }
    nsum = wave_reduce(nsum);
    if (lane == 0) red[32 + w] = nsum;
  } else if (mode == 1) {
    // LDS pos bit (j+3) mod 14 <- global bit j
    const float* srcf = vb + ((size_t)b << 20) + ((size_t)chunk << 14);
#pragma unroll
    for (int j = 0; j < 8; j++) {
      int B = j * 256 + t;
      half8 h;
#pragma unroll
      for (int e = 0; e < 8; e++) h[e] = (_Float16)srcf[e * 2048 + B];
      HB[swzB(B)] = h;
    }
  } else {
    // tile: 32 consecutive floats x 512 rows at stride 2048 floats
    const float4* src4 = ((const float4*)vb) + ((size_t)b << 18) + chunk * 8;
#pragma unroll
    for (int j = 0; j < 8; j++) {
      int B = j * 256 + t;
      int row = B >> 2;
      int c4 = (B & 3) * 2;
      float4 a = src4[row * 512 + c4], c = src4[row * 512 + c4 + 1];
      half8 h;
      h[0] = (_Float16)a.x; h[1] = (_Float16)a.y; h[2] = (_Float16)a.z; h[3] = (_Float16)a.w;
      h[4] = (_Float16)c.x; h[5] = (_Float16)c.y; h[6] = (_Float16)c.z; h[7] = (_Float16)c.w;
      HB[swzB(B)] = h;
    }
  }
  __syncthreads();

  int nwin;
  if (mode == 0) {
    nwin = 8;
#define DOWIN(P, WIN) { float v = wave_reduce(windowM<P>(HB, TS)); if (lane == 0) red[(WIN)*4 + w] = v; }
    DOWIN(3, 0) DOWIN(4, 1) DOWIN(5, 2) DOWIN(6, 3)
    DOWIN(7, 4) DOWIN(8, 5) DOWIN(9, 6) DOWIN(10, 7)
  } else if (mode == 1) {
    nwin = 3;
    DOWIN(3, 0) DOWIN(4, 1) DOWIN(5, 2)
  } else {
    nwin = 6;
    DOWIN(5, 0) DOWIN(6, 1) DOWIN(7, 2)
    DOWIN(8, 3) DOWIN(9, 4) DOWIN(10, 5)
#undef DOWIN
  }
  __syncthreads();

  // q = base - win per mode
  const int qbase = (mode == 0) ? 13 : (mode == 1) ? 16 : 5;
  if (t < nwin) {
    float s = red[t * 4] + red[t * 4 + 1] + red[t * 4 + 2] + red[t * 4 + 3];
    int q = qbase - t;
    if (use_part) ws[WS_PART + (b * 17 + q) * 64 + chunk] = s;
    else          atomicAdd(ws + WS_S + b * 17 + q, s);
  }
  if (mode == 0 && t == nwin) {
    float n = red[32] + red[33] + red[34] + red[35];
    if (use_part) ws[WS_NPART + b * 64 + chunk] = n;
    else          atomicAdd(ws + WS_N + b, n);
  }
}

__global__ void finalize_kernel(const float* __restrict__ ws, float* __restrict__ out,
                                int use_part) {
  int i = blockIdx.x * 256 + threadIdx.x;
  if (i < 544) {
    int b = i / 17;
    float s, n;
    if (use_part) {
      const float* sp = ws + WS_PART + i * 64;
      s = 0.f;
#pragma unroll 8
      for (int c = 0; c < 64; c++) s += sp[c];
      const float* np = ws + WS_NPART + b * 64;
      n = 0.f;
#pragma unroll 8
      for (int c = 0; c < 64; c++) n += np[c];
    } else {
      s = ws[WS_S + i];
      n = ws[WS_N + b];
    }
    out[i] = s / fmaxf(n, 1e-24f);
  }
}

extern "C" void kernel_launch(void* const* d_in, const int* in_sizes, int n_in,
                              void* d_out, int out_size, void* d_ws, size_t ws_size,
                              hipStream_t stream) {
  const float* vb  = (const float*)d_in[0];
  const float* wgt = (const float*)d_in[1];
  float* out = (float*)d_out;
  float* ws  = (float*)d_ws;
  int use_part = (ws_size >= (size_t)WS_NEED_BYTES) ? 1 : 0;

  hipMemsetAsync(d_ws, 0, 4096, stream);  // covers T + atomic-fallback S/n
  build_T_kernel<<<1, 256, 0, stream>>>(wgt, ws);
  passAll_kernel<<<6144, 256, 0, stream>>>(vb, ws, use_part);
  finalize_kernel<<<3, 256, 0, stream>>>(ws, out, use_part);
}

// Round 4
// 68.803 us; speedup vs baseline: 6.0742x; 1.1871x over previous
//
#include <hip/hip_runtime.h>
#include <math.h>

// Workspace layout (floats):
//   [0,256)          T     : full symmetric Re(U^H M U)
//   [256,800)        S     : atomic-fallback accumulators S[b][q]
//   [800,832)        n     : atomic-fallback squared norms
//   [1024,35840)     Spart : partials [b][q][chunk]  32*17*64
//   [35840,37888)    npart : norm partials [b][chunk] 32*64
#define WS_TU    0
#define WS_S     256
#define WS_N     800
#define WS_PART  1024
#define WS_NPART 35840
#define WS_NEED_BYTES ((WS_NPART + 2048) * 4)

typedef _Float16 half8 __attribute__((ext_vector_type(8)));
typedef float f32x4 __attribute__((ext_vector_type(4)));

__device__ inline float2 cmul2(float2 a, float2 b) {
  return make_float2(a.x * b.x - a.y * b.y, a.x * b.y + a.y * b.x);
}

__device__ inline int ringperm(int x) {
  if ((x >> 3) & 1) x ^= 4;
  if ((x >> 2) & 1) x ^= 2;
  if ((x >> 1) & 1) x ^= 1;
  if (x & 1)        x ^= 8;
  return x;
}

__device__ inline float2 yzy_elem(const float* wgt, int layer, int r, int c) {
  float2 prod = make_float2(1.f, 0.f);
#pragma unroll
  for (int k = 0; k < 4; k++) {
    float t0 = wgt[layer * 12 + 3 * k + 0];
    float t1 = wgt[layer * 12 + 3 * k + 1];
    float t2 = wgt[layer * 12 + 3 * k + 2];
    float s0, c0, s1, c1, s2, c2;
    sincosf(0.5f * t0, &s0, &c0);
    sincosf(0.5f * t1, &s1, &c1);
    sincosf(0.5f * t2, &s2, &c2);
    float A = c2 * c0, B = s2 * s0, C = c2 * s0, D = s2 * c0;
    float2 m00 = make_float2( c1 * (A - B), -s1 * (A + B));
    float2 m01 = make_float2(-c1 * (C + D),  s1 * (C - D));
    float2 m10 = make_float2( c1 * (C + D),  s1 * (C - D));
    float2 m11 = make_float2( c1 * (A - B),  s1 * (A + B));
    int rb = (r >> (3 - k)) & 1, cb = (c >> (3 - k)) & 1;
    float2 mm = rb ? (cb ? m11 : m10) : (cb ? m01 : m00);
    prod = cmul2(prod, mm);
  }
  return prod;
}

__global__ void build_T_kernel(const float* __restrict__ wgt, float* __restrict__ ws) {
  __shared__ float2 U[256], Y[256], W[256];
  const int t = threadIdx.x;
  const int r = t >> 4, c = t & 15;

  U[t] = yzy_elem(wgt, 0, r, c);
  __syncthreads();
  W[ringperm(r) * 16 + c] = U[t];
  __syncthreads(); U[t] = W[t]; __syncthreads();
  Y[t] = yzy_elem(wgt, 1, r, c);
  __syncthreads();
  {
    float2 s = make_float2(0.f, 0.f);
#pragma unroll
    for (int k = 0; k < 16; k++) {
      float2 pr = cmul2(Y[r * 16 + k], U[k * 16 + c]);
      s.x += pr.x; s.y += pr.y;
    }
    W[t] = s;
  }
  __syncthreads(); U[t] = W[t]; __syncthreads();
  W[ringperm(r) * 16 + c] = U[t];
  __syncthreads(); U[t] = W[t]; __syncthreads();
  Y[t] = yzy_elem(wgt, 2, r, c);
  __syncthreads();
  {
    float2 s = make_float2(0.f, 0.f);
#pragma unroll
    for (int k = 0; k < 16; k++) {
      float2 pr = cmul2(Y[r * 16 + k], U[k * 16 + c]);
      s.x += pr.x; s.y += pr.y;
    }
    W[t] = s;
  }
  __syncthreads(); U[t] = W[t]; __syncthreads();
  Y[t] = U[(r ^ 15) * 16 + c];
  __syncthreads();
  float s_re = 0.f;
#pragma unroll
  for (int k = 0; k < 16; k++) {
    float2 u = U[k * 16 + r], m = Y[k * 16 + c];
    s_re += u.x * m.x + u.y * m.y;
  }
  ws[WS_TU + t] = s_re;  // full symmetric T
}

// XOR-fold swizzle on 16B-block index
__device__ inline int swzB(int B) {
  int h = B >> 3;
  int f = (h ^ (h >> 3) ^ (h >> 6)) & 7;
  return B ^ f;
}

// Gram-window via MFMA, dual accumulator chains for ILP.
// LDS: 2048 16B blocks of 8 f16, block index swizzled. i-field at pos bits [P,P+4).
template <int P>
__device__ inline float windowM(const half8* __restrict__ HB, const float* __restrict__ Tr) {
  const int t = threadIdx.x;
  const int w = t >> 6, l = t & 63, g = l >> 4, i = l & 15;
  f32x4 h0 = {0.f, 0.f, 0.f, 0.f}, h1 = {0.f, 0.f, 0.f, 0.f};
#pragma unroll
  for (int s = 0; s < 4; s++) {
    int rest0 = (w << 5) | (s << 2) | g;        // 7-bit rest, chain 0
    int rest1 = (w << 5) | ((s + 4) << 2) | g;  // chain 1
    int rl0 = rest0 & ((1 << (P - 3)) - 1), rh0 = rest0 >> (P - 3);
    int rl1 = rest1 & ((1 << (P - 3)) - 1), rh1 = rest1 >> (P - 3);
    int pos0 = (rl0 << 3) | (i << P) | (rh0 << (P + 4));
    int pos1 = (rl1 << 3) | (i << P) | (rh1 << (P + 4));
    half8 f0 = HB[swzB(pos0 >> 3)];
    half8 f1 = HB[swzB(pos1 >> 3)];
    h0 = __builtin_amdgcn_mfma_f32_16x16x32_f16(f0, f0, h0, 0, 0, 0);
    h1 = __builtin_amdgcn_mfma_f32_16x16x32_f16(f1, f1, h1, 0, 0, 0);
  }
  float part = 0.f;
#pragma unroll
  for (int reg = 0; reg < 4; reg++) part = fmaf(Tr[reg], h0[reg] + h1[reg], part);
  return part;
}

// modes: 0 = identity contiguous chunk (p=3..10) + norms
//        1 = rot+3 contiguous chunk    (p=0,1,2 -> P=3,4,5)
//        2 = strided row tile          (p=11..16 -> P=5..10)
// bid mapping pairs mode0/mode1 on the same chunk 8 bids apart (same XCD, L2 reuse).
__global__ __launch_bounds__(256) void passAll_kernel(const float* __restrict__ vb,
                                                      float* ws, int use_part) {
  __shared__ half8 HB[2048];   // exactly 32 KB; reduce scratch aliases it later
  const int t = threadIdx.x;
  const int bid = blockIdx.x;

  int mode, idx;
  if (bid < 4096) {
    int gph = bid >> 4, s = bid & 15;
    mode = s >> 3;
    idx = gph * 8 + (s & 7);
  } else {
    mode = 2;
    idx = bid - 4096;
  }
  const int b = idx >> 6, chunk = idx & 63;
  const int l = t & 63, g = l >> 4, i = l & 15;

  // per-thread T values: T[g*4+reg][i] is all this lane ever needs
  float Treg[4];
#pragma unroll
  for (int reg = 0; reg < 4; reg++) Treg[reg] = ws[WS_TU + ((g * 4 + reg) << 4) + i];

  float nsum = 0.f;
  if (mode == 0) {
    const float4* src4 = ((const float4*)vb) + ((size_t)b << 18) + ((size_t)chunk << 12);
#pragma unroll
    for (int j = 0; j < 8; j++) {
      int B = j * 256 + t;
      float4 a = src4[2 * B], c = src4[2 * B + 1];
      nsum = fmaf(a.x, a.x, nsum); nsum = fmaf(a.y, a.y, nsum);
      nsum = fmaf(a.z, a.z, nsum); nsum = fmaf(a.w, a.w, nsum);
      nsum = fmaf(c.x, c.x, nsum); nsum = fmaf(c.y, c.y, nsum);
      nsum = fmaf(c.z, c.z, nsum); nsum = fmaf(c.w, c.w, nsum);
      half8 h;
      h[0] = (_Float16)a.x; h[1] = (_Float16)a.y; h[2] = (_Float16)a.z; h[3] = (_Float16)a.w;
      h[4] = (_Float16)c.x; h[5] = (_Float16)c.y; h[6] = (_Float16)c.z; h[7] = (_Float16)c.w;
      HB[swzB(B)] = h;
    }
  } else if (mode == 1) {
    // LDS pos bit (j+3) mod 14 <- global bit j
    const float* srcf = vb + ((size_t)b << 20) + ((size_t)chunk << 14);
#pragma unroll
    for (int j = 0; j < 8; j++) {
      int B = j * 256 + t;
      half8 h;
#pragma unroll
      for (int e = 0; e < 8; e++) h[e] = (_Float16)srcf[e * 2048 + B];
      HB[swzB(B)] = h;
    }
  } else {
    // tile: 32 consecutive floats x 512 rows at stride 2048 floats
    const float4* src4 = ((const float4*)vb) + ((size_t)b << 18) + chunk * 8;
#pragma unroll
    for (int j = 0; j < 8; j++) {
      int B = j * 256 + t;
      int row = B >> 2;
      int c4 = (B & 3) * 2;
      float4 a = src4[row * 512 + c4], c = src4[row * 512 + c4 + 1];
      half8 h;
      h[0] = (_Float16)a.x; h[1] = (_Float16)a.y; h[2] = (_Float16)a.z; h[3] = (_Float16)a.w;
      h[4] = (_Float16)c.x; h[5] = (_Float16)c.y; h[6] = (_Float16)c.z; h[7] = (_Float16)c.w;
      HB[swzB(B)] = h;
    }
  }
  __syncthreads();

  float part[8];
#pragma unroll
  for (int k = 0; k < 8; k++) part[k] = 0.f;

  int nwin;
#define DOWIN(P, WIN) part[WIN] = windowM<P>(HB, Treg);
  if (mode == 0) {
    nwin = 8;
    DOWIN(3, 0) DOWIN(4, 1) DOWIN(5, 2) DOWIN(6, 3)
    DOWIN(7, 4) DOWIN(8, 5) DOWIN(9, 6) DOWIN(10, 7)
  } else if (mode == 1) {
    nwin = 3;
    DOWIN(3, 0) DOWIN(4, 1) DOWIN(5, 2)
  } else {
    nwin = 6;
    DOWIN(5, 0) DOWIN(6, 1) DOWIN(7, 2)
    DOWIN(8, 3) DOWIN(9, 4) DOWIN(10, 5)
  }
#undef DOWIN
  __syncthreads();  // all reads of HB done; safe to alias reduce scratch

  float* red2 = (float*)HB;  // 9*256 floats = 9 KB
#pragma unroll
  for (int k = 0; k < 8; k++) red2[k * 256 + t] = part[k];
  red2[8 * 256 + t] = nsum;
  __syncthreads();

  // batched cross-block reduction: 32-thread group per window
  const int win = t >> 5, idx32 = t & 31;
  const float4* r4 = (const float4*)red2;
  float4 q0 = r4[win * 64 + idx32], q1 = r4[win * 64 + 32 + idx32];
  float s1 = (q0.x + q0.y + q0.z + q0.w) + (q1.x + q1.y + q1.z + q1.w);
#pragma unroll
  for (int off = 16; off; off >>= 1) s1 += __shfl_down(s1, off, 32);

  float s2 = 0.f;
  if (mode == 0 && win == 0) {  // norm is "window 8"
    float4 n0 = r4[8 * 64 + idx32], n1 = r4[8 * 64 + 32 + idx32];
    s2 = (n0.x + n0.y + n0.z + n0.w) + (n1.x + n1.y + n1.z + n1.w);
#pragma unroll
    for (int off = 16; off; off >>= 1) s2 += __shfl_down(s2, off, 32);
  }

  const int qbase = (mode == 0) ? 13 : (mode == 1) ? 16 : 5;
  if (idx32 == 0 && win < nwin) {
    int q = qbase - win;
    if (use_part) ws[WS_PART + (b * 17 + q) * 64 + chunk] = s1;
    else          atomicAdd(ws + WS_S + b * 17 + q, s1);
  }
  if (mode == 0 && t == 0) {
    if (use_part) ws[WS_NPART + b * 64 + chunk] = s2;
    else          atomicAdd(ws + WS_N + b, s2);
  }
}

__global__ void finalize_kernel(const float* __restrict__ ws, float* __restrict__ out,
                                int use_part) {
  int i = blockIdx.x * 256 + threadIdx.x;
  if (i < 544) {
    int b = i / 17;
    float s, n;
    if (use_part) {
      const float* sp = ws + WS_PART + i * 64;
      s = 0.f;
#pragma unroll 8
      for (int c = 0; c < 64; c++) s += sp[c];
      const float* np = ws + WS_NPART + b * 64;
      n = 0.f;
#pragma unroll 8
      for (int c = 0; c < 64; c++) n += np[c];
    } else {
      s = ws[WS_S + i];
      n = ws[WS_N + b];
    }
    out[i] = s / fmaxf(n, 1e-24f);
  }
}

extern "C" void kernel_launch(void* const* d_in, const int* in_sizes, int n_in,
                              void* d_out, int out_size, void* d_ws, size_t ws_size,
                              hipStream_t stream) {
  const float* vb  = (const float*)d_in[0];
  const float* wgt = (const float*)d_in[1];
  float* out = (float*)d_out;
  float* ws  = (float*)d_ws;
  int use_part = (ws_size >= (size_t)WS_NEED_BYTES) ? 1 : 0;

  hipMemsetAsync(d_ws, 0, 4096, stream);  // covers T + atomic-fallback S/n
  build_T_kernel<<<1, 256, 0, stream>>>(wgt, ws);
  passAll_kernel<<<6144, 256, 0, stream>>>(vb, ws, use_part);
  finalize_kernel<<<3, 256, 0, stream>>>(ws, out, use_part);
}

// Round 5
// 63.961 us; speedup vs baseline: 6.5340x; 1.0757x over previous
//
#include <hip/hip_runtime.h>
#include <math.h>

// Workspace layout (floats):
//   [0,256)          T     : full symmetric Re(U^H M U)
//   [256,800)        S     : atomic-fallback accumulators S[b][q]
//   [800,832)        n     : atomic-fallback squared norms
//   [1024,35840)     Spart : partials [b][q][chunk]  32*17*64
//   [35840,37888)    npart : norm partials [b][chunk] 32*64
#define WS_TU    0
#define WS_S     256
#define WS_N     800
#define WS_PART  1024
#define WS_NPART 35840
#define WS_NEED_BYTES ((WS_NPART + 2048) * 4)

typedef _Float16 half8 __attribute__((ext_vector_type(8)));
typedef float f32x4 __attribute__((ext_vector_type(4)));

__device__ inline float2 cmul2(float2 a, float2 b) {
  return make_float2(a.x * b.x - a.y * b.y, a.x * b.y + a.y * b.x);
}

__device__ inline int ringperm(int x) {
  if ((x >> 3) & 1) x ^= 4;
  if ((x >> 2) & 1) x ^= 2;
  if ((x >> 1) & 1) x ^= 1;
  if (x & 1)        x ^= 8;
  return x;
}

__device__ inline float2 yzy_elem(const float* wgt, int layer, int r, int c) {
  float2 prod = make_float2(1.f, 0.f);
#pragma unroll
  for (int k = 0; k < 4; k++) {
    float t0 = wgt[layer * 12 + 3 * k + 0];
    float t1 = wgt[layer * 12 + 3 * k + 1];
    float t2 = wgt[layer * 12 + 3 * k + 2];
    float s0, c0, s1, c1, s2, c2;
    sincosf(0.5f * t0, &s0, &c0);
    sincosf(0.5f * t1, &s1, &c1);
    sincosf(0.5f * t2, &s2, &c2);
    float A = c2 * c0, B = s2 * s0, C = c2 * s0, D = s2 * c0;
    float2 m00 = make_float2( c1 * (A - B), -s1 * (A + B));
    float2 m01 = make_float2(-c1 * (C + D),  s1 * (C - D));
    float2 m10 = make_float2( c1 * (C + D),  s1 * (C - D));
    float2 m11 = make_float2( c1 * (A - B),  s1 * (A + B));
    int rb = (r >> (3 - k)) & 1, cb = (c >> (3 - k)) & 1;
    float2 mm = rb ? (cb ? m11 : m10) : (cb ? m01 : m00);
    prod = cmul2(prod, mm);
  }
  return prod;
}

__global__ void build_T_kernel(const float* __restrict__ wgt, float* __restrict__ ws) {
  __shared__ float2 U[256], Y[256], W[256];
  const int t = threadIdx.x;
  const int r = t >> 4, c = t & 15;

  U[t] = yzy_elem(wgt, 0, r, c);
  __syncthreads();
  W[ringperm(r) * 16 + c] = U[t];
  __syncthreads(); U[t] = W[t]; __syncthreads();
  Y[t] = yzy_elem(wgt, 1, r, c);
  __syncthreads();
  {
    float2 s = make_float2(0.f, 0.f);
#pragma unroll
    for (int k = 0; k < 16; k++) {
      float2 pr = cmul2(Y[r * 16 + k], U[k * 16 + c]);
      s.x += pr.x; s.y += pr.y;
    }
    W[t] = s;
  }
  __syncthreads(); U[t] = W[t]; __syncthreads();
  W[ringperm(r) * 16 + c] = U[t];
  __syncthreads(); U[t] = W[t]; __syncthreads();
  Y[t] = yzy_elem(wgt, 2, r, c);
  __syncthreads();
  {
    float2 s = make_float2(0.f, 0.f);
#pragma unroll
    for (int k = 0; k < 16; k++) {
      float2 pr = cmul2(Y[r * 16 + k], U[k * 16 + c]);
      s.x += pr.x; s.y += pr.y;
    }
    W[t] = s;
  }
  __syncthreads(); U[t] = W[t]; __syncthreads();
  Y[t] = U[(r ^ 15) * 16 + c];
  __syncthreads();
  float s_re = 0.f;
#pragma unroll
  for (int k = 0; k < 16; k++) {
    float2 u = U[k * 16 + r], m = Y[k * 16 + c];
    s_re += u.x * m.x + u.y * m.y;
  }
  ws[WS_TU + t] = s_re;  // full symmetric T
}

// XOR-fold swizzle on 16B-block index
__device__ inline int swzB(int B) {
  int h = B >> 3;
  int f = (h ^ (h >> 3) ^ (h >> 6)) & 7;
  return B ^ f;
}

// Gram-window via MFMA, dual accumulator chains for ILP.
// LDS: 2048 16B blocks of 8 f16, block index swizzled. i-field at pos bits [P,P+4).
template <int P>
__device__ inline float windowM(const half8* __restrict__ HB, const float* __restrict__ Tr) {
  const int t = threadIdx.x;
  const int w = t >> 6, l = t & 63, g = l >> 4, i = l & 15;
  f32x4 h0 = {0.f, 0.f, 0.f, 0.f}, h1 = {0.f, 0.f, 0.f, 0.f};
#pragma unroll
  for (int s = 0; s < 4; s++) {
    int rest0 = (w << 5) | (s << 2) | g;        // 7-bit rest, chain 0
    int rest1 = (w << 5) | ((s + 4) << 2) | g;  // chain 1
    int rl0 = rest0 & ((1 << (P - 3)) - 1), rh0 = rest0 >> (P - 3);
    int rl1 = rest1 & ((1 << (P - 3)) - 1), rh1 = rest1 >> (P - 3);
    int pos0 = (rl0 << 3) | (i << P) | (rh0 << (P + 4));
    int pos1 = (rl1 << 3) | (i << P) | (rh1 << (P + 4));
    half8 f0 = HB[swzB(pos0 >> 3)];
    half8 f1 = HB[swzB(pos1 >> 3)];
    h0 = __builtin_amdgcn_mfma_f32_16x16x32_f16(f0, f0, h0, 0, 0, 0);
    h1 = __builtin_amdgcn_mfma_f32_16x16x32_f16(f1, f1, h1, 0, 0, 0);
  }
  float part = 0.f;
#pragma unroll
  for (int reg = 0; reg < 4; reg++) part = fmaf(Tr[reg], h0[reg] + h1[reg], part);
  return part;
}

// modes: 0 = contiguous chunk: image0 (identity, p=3..10) then in-register
//            transpose -> image1 (rot+3, p=0,1,2), plus norms. ONE global read.
//        2 = strided row tile (p=11..16), runs in the grid tail (L3-warm).
__global__ __launch_bounds__(256) void passAll_kernel(const float* __restrict__ vb,
                                                      float* ws, int use_part) {
  __shared__ half8 HB[2048];   // exactly 32 KB; reduce scratch aliases it later
  const int t = threadIdx.x;
  const int bid = blockIdx.x;

  const int mode = (bid < 2048) ? 0 : 2;
  const int idx = (bid < 2048) ? bid : bid - 2048;
  const int b = idx >> 6, chunk = idx & 63;
  const int l = t & 63, g = l >> 4, i = l & 15;

  // per-thread T values: T[g*4+reg][i] is all this lane ever needs
  float Treg[4];
#pragma unroll
  for (int reg = 0; reg < 4; reg++) Treg[reg] = ws[WS_TU + ((g * 4 + reg) << 4) + i];

  float nsum = 0.f;
  half8 h[8];  // mode 0: staged data kept in registers for the image1 transpose
  if (mode == 0) {
    const float4* src4 = ((const float4*)vb) + ((size_t)b << 18) + ((size_t)chunk << 12);
#pragma unroll
    for (int j = 0; j < 8; j++) {
      int B = j * 256 + t;
      float4 a = src4[2 * B], c = src4[2 * B + 1];
      nsum = fmaf(a.x, a.x, nsum); nsum = fmaf(a.y, a.y, nsum);
      nsum = fmaf(a.z, a.z, nsum); nsum = fmaf(a.w, a.w, nsum);
      nsum = fmaf(c.x, c.x, nsum); nsum = fmaf(c.y, c.y, nsum);
      nsum = fmaf(c.z, c.z, nsum); nsum = fmaf(c.w, c.w, nsum);
      half8 hh;
      hh[0] = (_Float16)a.x; hh[1] = (_Float16)a.y; hh[2] = (_Float16)a.z; hh[3] = (_Float16)a.w;
      hh[4] = (_Float16)c.x; hh[5] = (_Float16)c.y; hh[6] = (_Float16)c.z; hh[7] = (_Float16)c.w;
      h[j] = hh;
      HB[swzB(B)] = hh;
    }
  } else {
    // tile: 32 consecutive floats x 512 rows at stride 2048 floats
    const float4* src4 = ((const float4*)vb) + ((size_t)b << 18) + chunk * 8;
#pragma unroll
    for (int j = 0; j < 8; j++) {
      int B = j * 256 + t;
      int row = B >> 2;
      int c4 = (B & 3) * 2;
      float4 a = src4[row * 512 + c4], c = src4[row * 512 + c4 + 1];
      half8 hh;
      hh[0] = (_Float16)a.x; hh[1] = (_Float16)a.y; hh[2] = (_Float16)a.z; hh[3] = (_Float16)a.w;
      hh[4] = (_Float16)c.x; hh[5] = (_Float16)c.y; hh[6] = (_Float16)c.z; hh[7] = (_Float16)c.w;
      HB[swzB(B)] = hh;
    }
  }
  __syncthreads();

  float part[11];
#pragma unroll
  for (int k = 0; k < 11; k++) part[k] = 0.f;

  int nwin;
#define DOWIN(P, WIN) part[WIN] = windowM<P>(HB, Treg);
  if (mode == 0) {
    nwin = 11;
    // image0: p = P, q = 16 - p  -> win 0..7 <-> q 13..6
    DOWIN(3, 0) DOWIN(4, 1) DOWIN(5, 2) DOWIN(6, 3)
    DOWIN(7, 4) DOWIN(8, 5) DOWIN(9, 6) DOWIN(10, 7)
    __syncthreads();  // all image0 reads done
    // image1 (rot+3): element x[2048u + c] -> pos = c*8 + u.
    // Thread t holds h[j][e] = x[2048j + 8t + e]; block c = 8t+e gets {h[j][e]}_j.
#pragma unroll
    for (int e = 0; e < 8; e++) {
      half8 v;
#pragma unroll
      for (int j = 0; j < 8; j++) v[j] = h[j][e];
      HB[swzB(8 * t + e)] = v;
    }
    __syncthreads();
    // image1: p = P - 3 in {0,1,2}, q = 16 - p -> win 8,9,10 <-> q 16,15,14
    DOWIN(3, 8) DOWIN(4, 9) DOWIN(5, 10)
  } else {
    nwin = 6;
    // p = P + 6 in {11..16}, q = 10 - P -> win 0..5 <-> q 5..0
    DOWIN(5, 0) DOWIN(6, 1) DOWIN(7, 2)
    DOWIN(8, 3) DOWIN(9, 4) DOWIN(10, 5)
  }
#undef DOWIN
  __syncthreads();  // all reads of HB done; safe to alias reduce scratch

  float* red2 = (float*)HB;  // 12*256 floats = 12 KB
#pragma unroll
  for (int k = 0; k < 11; k++) red2[k * 256 + t] = part[k];
  red2[11 * 256 + t] = nsum;
  __syncthreads();

  // batched cross-block reduction: 16-thread group per value (12 live groups)
  const int win = t >> 4, idx16 = t & 15;
  const float4* r4 = (const float4*)red2;
  float4 q0 = r4[win * 64 + idx16],      q1 = r4[win * 64 + 16 + idx16];
  float4 q2 = r4[win * 64 + 32 + idx16], q3 = r4[win * 64 + 48 + idx16];
  float s1 = ((q0.x + q0.y) + (q0.z + q0.w)) + ((q1.x + q1.y) + (q1.z + q1.w)) +
             ((q2.x + q2.y) + (q2.z + q2.w)) + ((q3.x + q3.y) + (q3.z + q3.w));
#pragma unroll
  for (int off = 8; off; off >>= 1) s1 += __shfl_down(s1, off, 16);

  if (idx16 == 0) {
    if (mode == 0) {
      if (win < 11) {
        int q = (win < 8) ? (13 - win) : (24 - win);
        if (use_part) ws[WS_PART + (b * 17 + q) * 64 + chunk] = s1;
        else          atomicAdd(ws + WS_S + b * 17 + q, s1);
      } else if (win == 11) {
        if (use_part) ws[WS_NPART + b * 64 + chunk] = s1;
        else          atomicAdd(ws + WS_N + b, s1);
      }
    } else {
      if (win < 6) {
        int q = 5 - win;
        if (use_part) ws[WS_PART + (b * 17 + q) * 64 + chunk] = s1;
        else          atomicAdd(ws + WS_S + b * 17 + q, s1);
      }
    }
  }
}

__global__ void finalize_kernel(const float* __restrict__ ws, float* __restrict__ out,
                                int use_part) {
  int i = blockIdx.x * 256 + threadIdx.x;
  if (i < 544) {
    int b = i / 17;
    float s, n;
    if (use_part) {
      const float* sp = ws + WS_PART + i * 64;
      s = 0.f;
#pragma unroll 8
      for (int c = 0; c < 64; c++) s += sp[c];
      const float* np = ws + WS_NPART + b * 64;
      n = 0.f;
#pragma unroll 8
      for (int c = 0; c < 64; c++) n += np[c];
    } else {
      s = ws[WS_S + i];
      n = ws[WS_N + b];
    }
    out[i] = s / fmaxf(n, 1e-24f);
  }
}

extern "C" void kernel_launch(void* const* d_in, const int* in_sizes, int n_in,
                              void* d_out, int out_size, void* d_ws, size_t ws_size,
                              hipStream_t stream) {
  const float* vb  = (const float*)d_in[0];
  const float* wgt = (const float*)d_in[1];
  float* out = (float*)d_out;
  float* ws  = (float*)d_ws;
  int use_part = (ws_size >= (size_t)WS_NEED_BYTES) ? 1 : 0;

  hipMemsetAsync(d_ws, 0, 4096, stream);  // covers T + atomic-fallback S/n
  build_T_kernel<<<1, 256, 0, stream>>>(wgt, ws);
  passAll_kernel<<<4096, 256, 0, stream>>>(vb, ws, use_part);
  finalize_kernel<<<3, 256, 0, stream>>>(ws, out, use_part);
}